// Round 1
// baseline (1007.111 us; speedup 1.0000x reference)
//
#include <hip/hip_runtime.h>
#include <math.h>

#define N_K 5292
#define N_Q 1344
#define H_KV 384
#define NH_KD 128
#define OUT_DIM 512

// ---------------- zero scratch ----------------
__global__ void zero_f(float* __restrict__ p, int n) {
    int i = blockIdx.x * 256 + threadIdx.x;
    if (i < n) p[i] = 0.f;
}

// ---------------- GEMM: Y[m][n] = sum_k X[row(m)][k] * W[n][k], K = 256 ----------------
// mode 0: row(m) = m ; mode 1: strided 2x subsample of (63,84) grid
__global__ __launch_bounds__(256) void gemm_nt(const float* __restrict__ X,
                                               const float* __restrict__ W,
                                               float* __restrict__ Y,
                                               int M, int Ncols, int mode)
{
    __shared__ float Xs[16][68];   // [k][m], 68 = pad keeps rows 16B aligned, banks spread
    __shared__ float Ws[16][68];   // [k][n]
    const int t  = threadIdx.x;
    const int tx = t & 15, ty = t >> 4;
    const int m0 = blockIdx.y * 64, n0 = blockIdx.x * 64;
    const int lr = t >> 2;         // 0..63: tile row loaded by this thread
    const int lk = (t & 3) * 4;    // k offset 0,4,8,12

    int mrow = m0 + lr;
    int xsrc = -1;
    if (mrow < M) {
        if (mode == 1) {
            int b = mrow / N_Q;
            int i = mrow - b * N_Q;
            xsrc = b * N_K + (i / 42) * 168 + (i % 42) * 2;  // (2*r_)*84 + 2*c_
        } else xsrc = mrow;
    }
    int nrow = n0 + lr;
    int wsrc = (nrow < Ncols) ? nrow : -1;

    float c[4][4] = {};

    for (int k0 = 0; k0 < 256; k0 += 16) {
        float4 xv = make_float4(0.f, 0.f, 0.f, 0.f);
        float4 wv = make_float4(0.f, 0.f, 0.f, 0.f);
        if (xsrc >= 0) xv = *reinterpret_cast<const float4*>(X + xsrc * 256 + k0 + lk);
        if (wsrc >= 0) wv = *reinterpret_cast<const float4*>(W + wsrc * 256 + k0 + lk);
        __syncthreads();  // previous compute done reading LDS
        Xs[lk + 0][lr] = xv.x; Xs[lk + 1][lr] = xv.y; Xs[lk + 2][lr] = xv.z; Xs[lk + 3][lr] = xv.w;
        Ws[lk + 0][lr] = wv.x; Ws[lk + 1][lr] = wv.y; Ws[lk + 2][lr] = wv.z; Ws[lk + 3][lr] = wv.w;
        __syncthreads();
        #pragma unroll
        for (int kk = 0; kk < 16; ++kk) {
            float a[4], bb[4];
            *reinterpret_cast<float4*>(a)  = *reinterpret_cast<const float4*>(&Xs[kk][ty * 4]);
            *reinterpret_cast<float4*>(bb) = *reinterpret_cast<const float4*>(&Ws[kk][tx * 4]);
            #pragma unroll
            for (int i = 0; i < 4; ++i)
                #pragma unroll
                for (int j = 0; j < 4; ++j)
                    c[i][j] = fmaf(a[i], bb[j], c[i][j]);
        }
    }

    #pragma unroll
    for (int i = 0; i < 4; ++i) {
        int mr = m0 + ty * 4 + i;
        if (mr < M) {
            #pragma unroll
            for (int j = 0; j < 4; ++j) {
                int nc = n0 + tx * 4 + j;
                if (nc < Ncols) Y[mr * Ncols + nc] = c[i][j];
            }
        }
    }
}

// ---------------- per-column sum / sumsq (atomics into sums[0..cols), sums[cols..2*cols)) ----------------
__global__ __launch_bounds__(256) void col_stats(const float* __restrict__ Y, int rows, int cols,
                                                 float* __restrict__ sums)
{
    __shared__ float s1[4][64], s2[4][64];
    const int t = threadIdx.x;
    const int c = blockIdx.x * 64 + (t & 63);
    const int rg = t >> 6;
    const int rstep = gridDim.y * 4;
    float a = 0.f, b = 0.f;
    for (int r = blockIdx.y * 4 + rg; r < rows; r += rstep) {
        float v = Y[r * cols + c];
        a += v;
        b = fmaf(v, v, b);
    }
    s1[rg][t & 63] = a;
    s2[rg][t & 63] = b;
    __syncthreads();
    if (t < 64) {
        float ta = s1[0][t] + s1[1][t] + s1[2][t] + s1[3][t];
        float tb = s2[0][t] + s2[1][t] + s2[2][t] + s2[3][t];
        atomicAdd(&sums[blockIdx.x * 64 + t], ta);
        atomicAdd(&sums[cols + blockIdx.x * 64 + t], tb);
    }
}

// ---------------- BN finalize: scale = g*rsqrt(var+eps), shift = b - mu*scale ----------------
__global__ void finalize_bn(int cols, float inv_rows, const float* __restrict__ sums,
                            const float* __restrict__ g, const float* __restrict__ bb,
                            float* __restrict__ scale, float* __restrict__ shift)
{
    int c = blockIdx.x * 256 + threadIdx.x;
    if (c < cols) {
        float mu  = sums[c] * inv_rows;
        float var = fmaf(-mu, mu, sums[cols + c] * inv_rows);
        float sc  = g[c] * rsqrtf(var + 1e-5f);
        scale[c] = sc;
        shift[c] = fmaf(-mu, sc, bb[c]);
    }
}

// ---------------- flash attention + relative bias + hardswish epilogue ----------------
// grid: (21 q-tiles, 8 heads, 2 batch), block 256.
// thread t: q row = t&63, key-subset vg = t>>6 (16 keys/tile), accumulates all 32 v dims.
__global__ __launch_bounds__(256) void attn_kernel(
    const float* __restrict__ kv_y, const float* __restrict__ q_y,
    const float* __restrict__ kv_scale, const float* __restrict__ kv_shift,
    const float* __restrict__ q_scale, const float* __restrict__ q_shift,
    const float* __restrict__ bias_table, const int* __restrict__ bias_idxs,
    float* __restrict__ attn_out)
{
    const int qt = blockIdx.x, h = blockIdx.y, b = blockIdx.z;
    const int t = threadIdx.x;
    const int q = t & 63, vg = t >> 6;

    __shared__ float q_s[64][17];
    __shared__ float kv_s[64][52];     // [key][0:16]=K, [16:48]=V, 52 keeps rows 16B aligned
    __shared__ float bt_s[N_K];        // bias remapped to (dr*84+dc) indexing
    __shared__ float mpart[4][64];
    __shared__ int   kr_s[64];
    __shared__ int   kc_s[64];

    // bias_idxs row 0 enumerates the (dr,dc) table in identity order:
    // bt_s[dr*84+dc] = bias_table[h][rank(dr,dc)]
    for (int j = t; j < N_K; j += 256)
        bt_s[j] = bias_table[h * N_K + bias_idxs[j]];

    const int q0 = qt * 64;
    for (int idx = t; idx < 64 * 16; idx += 256) {
        int qq = idx >> 4, d = idx & 15;
        int ch = h * 16 + d;
        q_s[qq][d] = fmaf(q_y[(b * N_Q + q0 + qq) * NH_KD + ch], q_scale[ch], q_shift[ch]);
    }
    __syncthreads();

    float qreg[16];
    #pragma unroll
    for (int d = 0; d < 16; ++d) qreg[d] = q_s[q][d];

    const int qg  = q0 + q;
    const int rq2 = (qg / 42) * 2;
    const int cq2 = (qg % 42) * 2;

    float m = -1e30f;
    float lpart = 0.f;
    float acc[32];
    #pragma unroll
    for (int e = 0; e < 32; ++e) acc[e] = 0.f;

    const int kbase = vg * 16;

    for (int k0 = 0; k0 < N_K; k0 += 64) {
        __syncthreads();  // previous iteration done reading kv_s
        for (int idx = t; idx < 64 * 48; idx += 256) {
            int kk = idx / 48;
            int d  = idx - kk * 48;
            int kg = k0 + kk;
            int ch = h * 48 + d;
            float val = 0.f;
            if (kg < N_K) val = fmaf(kv_y[(b * N_K + kg) * H_KV + ch], kv_scale[ch], kv_shift[ch]);
            kv_s[kk][d] = val;
        }
        if (t < 64) {
            int kg = k0 + t;
            if (kg > N_K - 1) kg = N_K - 1;
            int rr = kg / 84;
            kr_s[t] = rr;
            kc_s[t] = kg - rr * 84;
        }
        __syncthreads();

        float s[16];
        float mloc = -1e30f;
        #pragma unroll
        for (int j = 0; j < 16; ++j) {
            int kl = kbase + j;
            const float* kp = &kv_s[kl][0];
            float dot = 0.f;
            #pragma unroll
            for (int d = 0; d < 16; ++d) dot = fmaf(qreg[d], kp[d], dot);
            int dr = rq2 - kr_s[kl]; dr = dr < 0 ? -dr : dr;
            int dc = cq2 - kc_s[kl]; dc = dc < 0 ? -dc : dc;
            float sc = fmaf(dot, 0.25f, bt_s[dr * 84 + dc]);
            s[j] = (k0 + kl < N_K) ? sc : -1e30f;
            mloc = fmaxf(mloc, s[j]);
        }
        mpart[vg][q] = mloc;
        __syncthreads();

        float mt = fmaxf(fmaxf(mpart[0][q], mpart[1][q]), fmaxf(mpart[2][q], mpart[3][q]));
        float mnew = fmaxf(m, mt);
        float alpha = __expf(m - mnew);
        m = mnew;
        lpart *= alpha;
        #pragma unroll
        for (int e = 0; e < 32; ++e) acc[e] *= alpha;
        #pragma unroll
        for (int j = 0; j < 16; ++j) {
            float p = __expf(s[j] - mnew);
            lpart += p;
            const float* vp = &kv_s[kbase + j][16];
            #pragma unroll
            for (int e = 0; e < 32; ++e) acc[e] = fmaf(p, vp[e], acc[e]);
        }
    }

    // cross-vg reduction of l (via mpart) and acc (via kv_s space)
    __syncthreads();
    mpart[vg][q] = lpart;
    float* red = &kv_s[0][0];  // 4*64*8 = 2048 floats, fits
    float out8[8];
    #pragma unroll
    for (int cch = 0; cch < 4; ++cch) {
        __syncthreads();
        #pragma unroll
        for (int u = 0; u < 8; ++u) red[(vg * 64 + q) * 8 + u] = acc[cch * 8 + u];
        __syncthreads();
        if (vg == cch) {
            #pragma unroll
            for (int u = 0; u < 8; ++u)
                out8[u] = red[q * 8 + u] + red[(64 + q) * 8 + u]
                        + red[(128 + q) * 8 + u] + red[(192 + q) * 8 + u];
        }
    }
    float ltot = mpart[0][q] + mpart[1][q] + mpart[2][q] + mpart[3][q];
    float inv = 1.f / ltot;
    const int row = b * N_Q + qg;
    #pragma unroll
    for (int u = 0; u < 8; ++u) {
        float v = out8[u] * inv;
        float hs = v * fminf(fmaxf(v + 3.f, 0.f), 6.f) * (1.f / 6.f);  // hardswish
        attn_out[row * 256 + h * 32 + vg * 8 + u] = hs;
    }
}

// ---------------- final BN apply ----------------
__global__ __launch_bounds__(256) void bn_apply(const float* __restrict__ Y,
                                                const float* __restrict__ scale,
                                                const float* __restrict__ shift,
                                                float* __restrict__ out, int total)
{
    int i = (blockIdx.x * 256 + threadIdx.x) * 4;
    if (i < total) {
        float4 v = *reinterpret_cast<const float4*>(Y + i);
        int c = i & (OUT_DIM - 1);
        float4 o;
        o.x = fmaf(v.x, scale[c + 0], shift[c + 0]);
        o.y = fmaf(v.y, scale[c + 1], shift[c + 1]);
        o.z = fmaf(v.z, scale[c + 2], shift[c + 2]);
        o.w = fmaf(v.w, scale[c + 3], shift[c + 3]);
        *reinterpret_cast<float4*>(out + i) = o;
    }
}

extern "C" void kernel_launch(void* const* d_in, const int* in_sizes, int n_in,
                              void* d_out, int out_size, void* d_ws, size_t ws_size,
                              hipStream_t stream) {
    (void)in_sizes; (void)n_in; (void)out_size; (void)ws_size;
    const float* x      = (const float*)d_in[0];
    const float* kv_w   = (const float*)d_in[1];
    const float* kv_g   = (const float*)d_in[2];
    const float* kv_b   = (const float*)d_in[3];
    const float* q_w    = (const float*)d_in[4];
    const float* q_g    = (const float*)d_in[5];
    const float* q_b    = (const float*)d_in[6];
    const float* proj_w = (const float*)d_in[7];
    const float* proj_g = (const float*)d_in[8];
    const float* proj_b = (const float*)d_in[9];
    const float* bias_table = (const float*)d_in[10];
    const int*   bias_idxs  = (const int*)d_in[11];
    float* out = (float*)d_out;

    float* ws = (float*)d_ws;
    float* kv_y     = ws;                       // 10584*384
    float* q_y      = kv_y + 10584 * 384;       // 2688*128
    float* attn_o   = q_y + 2688 * 128;         // 2688*256
    float* proj_y   = attn_o + 2688 * 256;      // 2688*512
    float* sums_kv  = proj_y + 2688 * 512;      // 768
    float* sums_q   = sums_kv + 768;            // 256
    float* sums_p   = sums_q + 256;             // 1024
    float* kv_scale = sums_p + 1024;            // 384
    float* kv_shift = kv_scale + 384;           // 384
    float* q_scale  = kv_shift + 384;           // 128
    float* q_shift  = q_scale + 128;            // 128
    float* p_scale  = q_shift + 128;            // 512
    float* p_shift  = p_scale + 512;            // 512

    // zero the stats accumulators (re-poisoned to 0xAA before every launch)
    zero_f<<<8, 256, 0, stream>>>(sums_kv, 2048);

    // kv = x @ kv_w^T ; stats ; BN params
    gemm_nt<<<dim3(6, 166), 256, 0, stream>>>(x, kv_w, kv_y, 10584, 384, 0);
    col_stats<<<dim3(6, 32), 256, 0, stream>>>(kv_y, 10584, 384, sums_kv);
    finalize_bn<<<2, 256, 0, stream>>>(384, 1.f / 10584.f, sums_kv, kv_g, kv_b, kv_scale, kv_shift);

    // q = xs @ q_w^T ; stats ; BN params
    gemm_nt<<<dim3(2, 42), 256, 0, stream>>>(x, q_w, q_y, 2688, 128, 1);
    col_stats<<<dim3(2, 32), 256, 0, stream>>>(q_y, 2688, 128, sums_q);
    finalize_bn<<<1, 256, 0, stream>>>(128, 1.f / 2688.f, sums_q, q_g, q_b, q_scale, q_shift);

    // attention (BN applied on the fly) + hardswish epilogue
    attn_kernel<<<dim3(21, 8, 2), 256, 0, stream>>>(kv_y, q_y, kv_scale, kv_shift,
                                                    q_scale, q_shift, bias_table, bias_idxs, attn_o);

    // proj = hs @ proj_w^T ; stats ; BN apply -> out
    gemm_nt<<<dim3(8, 42), 256, 0, stream>>>(attn_o, proj_w, proj_y, 2688, 512, 0);
    col_stats<<<dim3(8, 32), 256, 0, stream>>>(proj_y, 2688, 512, sums_p);
    finalize_bn<<<2, 256, 0, stream>>>(512, 1.f / 2688.f, sums_p, proj_g, proj_b, p_scale, p_shift);
    bn_apply<<<1344, 256, 0, stream>>>(proj_y, p_scale, p_shift, out, 2688 * 512);
}

// Round 2
// 552.847 us; speedup vs baseline: 1.8217x; 1.8217x over previous
//
#include <hip/hip_runtime.h>
#include <math.h>

#define N_K 5292
#define N_Q 1344
#define H_KV 384
#define NH_KD 128
#define OUT_DIM 512
#define NROWS 21504   // 2*8*1344 (b,h,q) rows of partials

// ---------------- zero scratch ----------------
__global__ void zero_f(float* __restrict__ p, int n) {
    int i = blockIdx.x * 256 + threadIdx.x;
    if (i < n) p[i] = 0.f;
}

// ---------------- GEMM: Y[m][n] = sum_k X[row(m)][k] * W[n][k], K = 256 ----------------
__global__ __launch_bounds__(256) void gemm_nt(const float* __restrict__ X,
                                               const float* __restrict__ W,
                                               float* __restrict__ Y,
                                               int M, int Ncols, int mode)
{
    __shared__ float Xs[16][68];
    __shared__ float Ws[16][68];
    const int t  = threadIdx.x;
    const int tx = t & 15, ty = t >> 4;
    const int m0 = blockIdx.y * 64, n0 = blockIdx.x * 64;
    const int lr = t >> 2;
    const int lk = (t & 3) * 4;

    int mrow = m0 + lr;
    int xsrc = -1;
    if (mrow < M) {
        if (mode == 1) {
            int b = mrow / N_Q;
            int i = mrow - b * N_Q;
            xsrc = b * N_K + (i / 42) * 168 + (i % 42) * 2;
        } else xsrc = mrow;
    }
    int nrow = n0 + lr;
    int wsrc = (nrow < Ncols) ? nrow : -1;

    float c[4][4] = {};

    for (int k0 = 0; k0 < 256; k0 += 16) {
        float4 xv = make_float4(0.f, 0.f, 0.f, 0.f);
        float4 wv = make_float4(0.f, 0.f, 0.f, 0.f);
        if (xsrc >= 0) xv = *reinterpret_cast<const float4*>(X + xsrc * 256 + k0 + lk);
        if (wsrc >= 0) wv = *reinterpret_cast<const float4*>(W + wsrc * 256 + k0 + lk);
        __syncthreads();
        Xs[lk + 0][lr] = xv.x; Xs[lk + 1][lr] = xv.y; Xs[lk + 2][lr] = xv.z; Xs[lk + 3][lr] = xv.w;
        Ws[lk + 0][lr] = wv.x; Ws[lk + 1][lr] = wv.y; Ws[lk + 2][lr] = wv.z; Ws[lk + 3][lr] = wv.w;
        __syncthreads();
        #pragma unroll
        for (int kk = 0; kk < 16; ++kk) {
            float a[4], bb[4];
            *reinterpret_cast<float4*>(a)  = *reinterpret_cast<const float4*>(&Xs[kk][ty * 4]);
            *reinterpret_cast<float4*>(bb) = *reinterpret_cast<const float4*>(&Ws[kk][tx * 4]);
            #pragma unroll
            for (int i = 0; i < 4; ++i)
                #pragma unroll
                for (int j = 0; j < 4; ++j)
                    c[i][j] = fmaf(a[i], bb[j], c[i][j]);
        }
    }

    #pragma unroll
    for (int i = 0; i < 4; ++i) {
        int mr = m0 + ty * 4 + i;
        if (mr < M) {
            #pragma unroll
            for (int j = 0; j < 4; ++j) {
                int nc = n0 + tx * 4 + j;
                if (nc < Ncols) Y[mr * Ncols + nc] = c[i][j];
            }
        }
    }
}

// ---------------- per-column sum / sumsq ----------------
__global__ __launch_bounds__(256) void col_stats(const float* __restrict__ Y, int rows, int cols,
                                                 float* __restrict__ sums)
{
    __shared__ float s1[4][64], s2[4][64];
    const int t = threadIdx.x;
    const int c = blockIdx.x * 64 + (t & 63);
    const int rg = t >> 6;
    const int rstep = gridDim.y * 4;
    float a = 0.f, b = 0.f;
    for (int r = blockIdx.y * 4 + rg; r < rows; r += rstep) {
        float v = Y[r * cols + c];
        a += v;
        b = fmaf(v, v, b);
    }
    s1[rg][t & 63] = a;
    s2[rg][t & 63] = b;
    __syncthreads();
    if (t < 64) {
        float ta = s1[0][t] + s1[1][t] + s1[2][t] + s1[3][t];
        float tb = s2[0][t] + s2[1][t] + s2[2][t] + s2[3][t];
        atomicAdd(&sums[blockIdx.x * 64 + t], ta);
        atomicAdd(&sums[cols + blockIdx.x * 64 + t], tb);
    }
}

// ---------------- BN finalize (post lets us fold attention SCALE into q) ----------------
__global__ void finalize_bn(int cols, float inv_rows, float post, const float* __restrict__ sums,
                            const float* __restrict__ g, const float* __restrict__ bb,
                            float* __restrict__ scale, float* __restrict__ shift)
{
    int c = blockIdx.x * 256 + threadIdx.x;
    if (c < cols) {
        float mu  = sums[c] * inv_rows;
        float var = fmaf(-mu, mu, sums[cols + c] * inv_rows);
        float sc  = g[c] * rsqrtf(var + 1e-5f) * post;
        scale[c] = sc;
        shift[c] = fmaf(-mu, sc, bb[c] * post);
    }
}

// ---------------- normalize rows in place (cols multiple of 4) ----------------
__global__ __launch_bounds__(256) void norm_inplace(float* __restrict__ Y,
                                                    const float* __restrict__ scale,
                                                    const float* __restrict__ shift,
                                                    int nf4, int cols4)
{
    int f = blockIdx.x * 256 + threadIdx.x;
    if (f < nf4) {
        int c = (f % cols4) * 4;
        float4 v = reinterpret_cast<float4*>(Y)[f];
        v.x = fmaf(v.x, scale[c + 0], shift[c + 0]);
        v.y = fmaf(v.y, scale[c + 1], shift[c + 1]);
        v.z = fmaf(v.z, scale[c + 2], shift[c + 2]);
        v.w = fmaf(v.w, scale[c + 3], shift[c + 3]);
        reinterpret_cast<float4*>(Y)[f] = v;
    }
}

// ---------------- bias remap: bt_r[h][dr*84+dc] = bf16(bias_table[h][rank]) ----------------
__global__ void bias_remap(const float* __restrict__ bias_table, const int* __restrict__ bias_idxs,
                           unsigned short* __restrict__ bt_r, int n_off)
{
    int i = blockIdx.x * 256 + threadIdx.x;
    if (i < 8 * N_K) {
        int h = i / N_K, j = i - h * N_K;
        float v = bias_table[h * n_off + bias_idxs[j]];
        unsigned u = __float_as_uint(v);
        u += 0x7FFFu + ((u >> 16) & 1u);   // round-to-nearest-even bf16
        bt_r[i] = (unsigned short)(u >> 16);
    }
}

// ---------------- flash attention, 4-way key split, per-wave online softmax ----------------
// grid (21 qtiles, 8 heads, 8 = b*4+ks). block 256. thread: q=t&63, vg=t>>6 (wave id).
// Each wave-group vg keeps independent (m,l,acc[32]) over its 16-key slices; merged once at end.
__global__ __launch_bounds__(256, 5) void attn_kernel(
    const float* __restrict__ kv_n, const float* __restrict__ q_n,
    const unsigned short* __restrict__ bt_r,
    float* __restrict__ pm, float* __restrict__ pl, float* __restrict__ pacc)
{
    const int qt = blockIdx.x, h = blockIdx.y;
    const int b = blockIdx.z >> 2, ks = blockIdx.z & 3;
    const int t = threadIdx.x;
    const int q = t & 63, vg = t >> 6;

    __shared__ float kv_s[64][52];          // [key][0:16]=K, [16:48]=V
    __shared__ float q_s[64][16];
    __shared__ unsigned short bt_s[5296];
    __shared__ float mpart[4][64];

    // bias table (bf16) -> LDS, contiguous copy
    {
        const unsigned* src = reinterpret_cast<const unsigned*>(bt_r + h * N_K);
        unsigned* dst = reinterpret_cast<unsigned*>(bt_s);
        for (int j = t; j < N_K / 2; j += 256) dst[j] = src[j];
    }
    // q tile -> LDS (pre-normalized & pre-scaled by 0.25)
    const int q0 = qt * 64;
    {
        int qq = t >> 2, d = (t & 3) * 4;
        *reinterpret_cast<float4*>(&q_s[qq][d]) =
            *reinterpret_cast<const float4*>(q_n + (b * N_Q + q0 + qq) * NH_KD + h * 16 + d);
    }
    __syncthreads();

    float qreg[16];
    #pragma unroll
    for (int d = 0; d < 16; ++d) qreg[d] = q_s[q][d];

    const int qg  = q0 + q;
    const int rq2 = (qg / 42) * 2;
    const int cq2 = (qg % 42) * 2;

    float m = -1e30f, l = 0.f;
    float acc[32];
    #pragma unroll
    for (int e = 0; e < 32; ++e) acc[e] = 0.f;

    const int kstart = ks * 1344;
    const int kend   = (kstart + 1344 < N_K) ? kstart + 1344 : N_K;

    for (int k0 = kstart; k0 < kend; k0 += 64) {
        __syncthreads();
        // stage 64 keys x 48ch, float4, pre-normalized
        #pragma unroll
        for (int i = 0; i < 3; ++i) {
            int f = t + i * 256;
            int kk = f / 12, d4 = f - kk * 12;
            int kg = k0 + kk;
            float4 v = make_float4(0.f, 0.f, 0.f, 0.f);
            if (kg < N_K)
                v = *reinterpret_cast<const float4*>(kv_n + (b * N_K + kg) * H_KV + h * 48 + d4 * 4);
            *reinterpret_cast<float4*>(&kv_s[kk][d4 * 4]) = v;
        }
        __syncthreads();

        const int kg0 = k0 + vg * 16;
        int kr = kg0 / 84;
        int kc = kg0 - kr * 84;

        float s[16];
        float mloc = -1e30f;
        #pragma unroll
        for (int j = 0; j < 16; ++j) {
            const float* kp = &kv_s[vg * 16 + j][0];
            float dot = 0.f;
            #pragma unroll
            for (int d = 0; d < 16; ++d) dot = fmaf(qreg[d], kp[d], dot);
            int dr = rq2 - kr; dr = dr < 0 ? -dr : dr;
            int dc = cq2 - kc; dc = dc < 0 ? -dc : dc;
            float bias = __uint_as_float(((unsigned)bt_s[dr * 84 + dc]) << 16);
            float sc = dot + bias;                     // q pre-scaled by 0.25
            s[j] = (kg0 + j < N_K) ? sc : -1e30f;
            mloc = fmaxf(mloc, s[j]);
            ++kc; if (kc == 84) { kc = 0; ++kr; }
        }
        float mnew = fmaxf(m, mloc);
        float alpha = __expf(m - mnew);
        m = mnew;
        l *= alpha;
        #pragma unroll
        for (int e = 0; e < 32; ++e) acc[e] *= alpha;
        #pragma unroll
        for (int j = 0; j < 16; ++j) {
            float p = __expf(s[j] - mnew);
            l += p;
            const float* vp = &kv_s[vg * 16 + j][16];
            #pragma unroll
            for (int e = 0; e < 32; ++e) acc[e] = fmaf(p, vp[e], acc[e]);
        }
    }

    // merge the 4 wave-groups: global max, rescale, reduce l and acc
    mpart[vg][q] = m;
    __syncthreads();
    float M = fmaxf(fmaxf(mpart[0][q], mpart[1][q]), fmaxf(mpart[2][q], mpart[3][q]));
    float sc = __expf(m - M);
    l *= sc;
    #pragma unroll
    for (int e = 0; e < 32; ++e) acc[e] *= sc;
    __syncthreads();
    mpart[vg][q] = l;
    __syncthreads();
    float L = mpart[0][q] + mpart[1][q] + mpart[2][q] + mpart[3][q];

    float* red = &kv_s[0][0];
    float out8[8];
    #pragma unroll
    for (int cch = 0; cch < 4; ++cch) {
        __syncthreads();
        #pragma unroll
        for (int u = 0; u < 8; ++u) red[(vg * 64 + q) * 8 + u] = acc[cch * 8 + u];
        __syncthreads();
        if (vg == cch) {
            #pragma unroll
            for (int u = 0; u < 8; ++u)
                out8[u] = red[q * 8 + u] + red[(64 + q) * 8 + u]
                        + red[(128 + q) * 8 + u] + red[(192 + q) * 8 + u];
        }
    }

    const int prow = ((ks * 2 + b) * 8 + h) * N_Q + qg;   // = ks*NROWS + (b*8+h)*1344 + qg
    if (vg == 0) { pm[prow] = M; pl[prow] = L; }
    *reinterpret_cast<float4*>(pacc + prow * 32 + vg * 8)     = *reinterpret_cast<float4*>(&out8[0]);
    *reinterpret_cast<float4*>(pacc + prow * 32 + vg * 8 + 4) = *reinterpret_cast<float4*>(&out8[4]);
}

// ---------------- combine 4 key-split partials + hardswish ----------------
__global__ __launch_bounds__(256) void combine_kernel(const float* __restrict__ pm,
                                                      const float* __restrict__ pl,
                                                      const float* __restrict__ pacc,
                                                      float* __restrict__ attn_o)
{
    int i = blockIdx.x * 256 + threadIdx.x;      // < NROWS*32
    int r = i >> 5, e = i & 31;
    float m0 = pm[r], m1 = pm[NROWS + r], m2 = pm[2 * NROWS + r], m3 = pm[3 * NROWS + r];
    float M = fmaxf(fmaxf(m0, m1), fmaxf(m2, m3));
    float w0 = __expf(m0 - M), w1 = __expf(m1 - M), w2 = __expf(m2 - M), w3 = __expf(m3 - M);
    float L = pl[r] * w0 + pl[NROWS + r] * w1 + pl[2 * NROWS + r] * w2 + pl[3 * NROWS + r] * w3;
    float v = pacc[r * 32 + e] * w0 + pacc[(NROWS + r) * 32 + e] * w1
            + pacc[(2 * NROWS + r) * 32 + e] * w2 + pacc[(3 * NROWS + r) * 32 + e] * w3;
    v /= L;
    float hs = v * fminf(fmaxf(v + 3.f, 0.f), 6.f) * (1.f / 6.f);
    int q = r % N_Q;
    int bh = r / N_Q;
    int h = bh & 7, b = bh >> 3;
    attn_o[(b * N_Q + q) * 256 + h * 32 + e] = hs;
}

// ---------------- final BN apply ----------------
__global__ __launch_bounds__(256) void bn_apply(const float* __restrict__ Y,
                                                const float* __restrict__ scale,
                                                const float* __restrict__ shift,
                                                float* __restrict__ out, int total)
{
    int i = (blockIdx.x * 256 + threadIdx.x) * 4;
    if (i < total) {
        float4 v = *reinterpret_cast<const float4*>(Y + i);
        int c = i & (OUT_DIM - 1);
        float4 o;
        o.x = fmaf(v.x, scale[c + 0], shift[c + 0]);
        o.y = fmaf(v.y, scale[c + 1], shift[c + 1]);
        o.z = fmaf(v.z, scale[c + 2], shift[c + 2]);
        o.w = fmaf(v.w, scale[c + 3], shift[c + 3]);
        *reinterpret_cast<float4*>(out + i) = o;
    }
}

extern "C" void kernel_launch(void* const* d_in, const int* in_sizes, int n_in,
                              void* d_out, int out_size, void* d_ws, size_t ws_size,
                              hipStream_t stream) {
    (void)n_in; (void)out_size; (void)ws_size;
    const float* x      = (const float*)d_in[0];
    const float* kv_w   = (const float*)d_in[1];
    const float* kv_g   = (const float*)d_in[2];
    const float* kv_b   = (const float*)d_in[3];
    const float* q_w    = (const float*)d_in[4];
    const float* q_g    = (const float*)d_in[5];
    const float* q_b    = (const float*)d_in[6];
    const float* proj_w = (const float*)d_in[7];
    const float* proj_g = (const float*)d_in[8];
    const float* proj_b = (const float*)d_in[9];
    const float* bias_table = (const float*)d_in[10];
    const int*   bias_idxs  = (const int*)d_in[11];
    const int    n_off = in_sizes[10] / 8;
    float* out = (float*)d_out;

    float* ws = (float*)d_ws;
    float* kv_y     = ws;                          // 10584*384 = 4,064,256
    float* q_y      = kv_y + 10584 * 384;          // 344,064
    float* attn_o   = q_y + 2688 * 128;            // 688,128
    float* pacc     = attn_o + 2688 * 256;         // 4*21504*32 = 2,752,512
    float* proj_y   = pacc;                        // overlays pacc (pacc dead by proj GEMM)
    float* pm       = pacc + 4 * NROWS * 32;       // 86,016
    float* pl       = pm + 4 * NROWS;              // 86,016
    float* sums_kv  = pl + 4 * NROWS;              // 768
    float* sums_q   = sums_kv + 768;               // 256
    float* sums_p   = sums_q + 256;                // 1024
    float* kv_scale = sums_p + 1024;               // 384
    float* kv_shift = kv_scale + 384;              // 384
    float* q_scale  = kv_shift + 384;              // 128
    float* q_shift  = q_scale + 128;               // 128
    float* p_scale  = q_shift + 128;               // 512
    float* p_shift  = p_scale + 512;               // 512
    unsigned short* bt_r = (unsigned short*)(p_shift + 512);  // 8*5292 bf16

    zero_f<<<8, 256, 0, stream>>>(sums_kv, 2048);

    // kv = BN(x @ kv_w^T), normalized in place
    gemm_nt<<<dim3(6, 166), 256, 0, stream>>>(x, kv_w, kv_y, 10584, 384, 0);
    col_stats<<<dim3(6, 32), 256, 0, stream>>>(kv_y, 10584, 384, sums_kv);
    finalize_bn<<<2, 256, 0, stream>>>(384, 1.f / 10584.f, 1.f, sums_kv, kv_g, kv_b, kv_scale, kv_shift);
    norm_inplace<<<3970, 256, 0, stream>>>(kv_y, kv_scale, kv_shift, 10584 * 96, 96);

    // q = BN(xs @ q_w^T) * 0.25 (attention scale folded in), normalized in place
    gemm_nt<<<dim3(2, 42), 256, 0, stream>>>(x, q_w, q_y, 2688, 128, 1);
    col_stats<<<dim3(2, 32), 256, 0, stream>>>(q_y, 2688, 128, sums_q);
    finalize_bn<<<1, 256, 0, stream>>>(128, 1.f / 2688.f, 0.25f, sums_q, q_g, q_b, q_scale, q_shift);
    norm_inplace<<<336, 256, 0, stream>>>(q_y, q_scale, q_shift, 2688 * 32, 32);

    // per-head remapped bias table (bf16)
    bias_remap<<<166, 256, 0, stream>>>(bias_table, bias_idxs, bt_r, n_off);

    // flash attention, 4-way key split -> partials -> combine (+hardswish)
    attn_kernel<<<dim3(21, 8, 8), 256, 0, stream>>>(kv_y, q_y, bt_r, pm, pl, pacc);
    combine_kernel<<<2688, 256, 0, stream>>>(pm, pl, pacc, attn_o);

    // proj = BN(hs @ proj_w^T)
    gemm_nt<<<dim3(8, 42), 256, 0, stream>>>(attn_o, proj_w, proj_y, 2688, 512, 0);
    col_stats<<<dim3(8, 32), 256, 0, stream>>>(proj_y, 2688, 512, sums_p);
    finalize_bn<<<2, 256, 0, stream>>>(512, 1.f / 2688.f, 1.f, sums_p, proj_g, proj_b, p_scale, p_shift);
    bn_apply<<<1344, 256, 0, stream>>>(proj_y, p_scale, p_shift, out, 2688 * 512);
}

// Round 3
// 304.352 us; speedup vs baseline: 3.3090x; 1.8165x over previous
//
#include <hip/hip_runtime.h>
#include <math.h>

#define N_K 5292
#define N_Q 1344
#define H_KV 384
#define NH_KD 128
#define OUT_DIM 512
#define NROWS 21504   // 2*8*1344 (b,h,q) rows of partials

typedef float f32x4 __attribute__((ext_vector_type(4)));
typedef short short8 __attribute__((ext_vector_type(8)));

__device__ __forceinline__ unsigned short f2bf(float x) {
    unsigned u = __float_as_uint(x);
    u += 0x7FFFu + ((u >> 16) & 1u);     // RNE to bf16
    return (unsigned short)(u >> 16);
}

// ---------------- zero scratch ----------------
__global__ void zero_f(float* __restrict__ p, int n) {
    int i = blockIdx.x * 256 + threadIdx.x;
    if (i < n) p[i] = 0.f;
}

// ---- GEMM: Y[m][n] = sum_k X[row(m)][k] * W[n][k], K=256, fused col sum/sumsq ----
__global__ __launch_bounds__(256) void gemm_nt(const float* __restrict__ X,
                                               const float* __restrict__ W,
                                               float* __restrict__ Y,
                                               float* __restrict__ sums,
                                               int M, int Ncols, int mode)
{
    __shared__ float Xs[16][68];
    __shared__ float Ws[16][68];
    const int t  = threadIdx.x;
    const int tx = t & 15, ty = t >> 4;
    const int m0 = blockIdx.y * 64, n0 = blockIdx.x * 64;
    const int lr = t >> 2;
    const int lk = (t & 3) * 4;

    int mrow = m0 + lr;
    int xsrc = -1;
    if (mrow < M) {
        if (mode == 1) {
            int b = mrow / N_Q;
            int i = mrow - b * N_Q;
            xsrc = b * N_K + (i / 42) * 168 + (i % 42) * 2;
        } else xsrc = mrow;
    }
    int nrow = n0 + lr;
    int wsrc = (nrow < Ncols) ? nrow : -1;

    float c[4][4] = {};

    for (int k0 = 0; k0 < 256; k0 += 16) {
        float4 xv = make_float4(0.f, 0.f, 0.f, 0.f);
        float4 wv = make_float4(0.f, 0.f, 0.f, 0.f);
        if (xsrc >= 0) xv = *reinterpret_cast<const float4*>(X + (size_t)xsrc * 256 + k0 + lk);
        if (wsrc >= 0) wv = *reinterpret_cast<const float4*>(W + (size_t)wsrc * 256 + k0 + lk);
        __syncthreads();
        Xs[lk + 0][lr] = xv.x; Xs[lk + 1][lr] = xv.y; Xs[lk + 2][lr] = xv.z; Xs[lk + 3][lr] = xv.w;
        Ws[lk + 0][lr] = wv.x; Ws[lk + 1][lr] = wv.y; Ws[lk + 2][lr] = wv.z; Ws[lk + 3][lr] = wv.w;
        __syncthreads();
        #pragma unroll
        for (int kk = 0; kk < 16; ++kk) {
            float a[4], bb[4];
            *reinterpret_cast<float4*>(a)  = *reinterpret_cast<const float4*>(&Xs[kk][ty * 4]);
            *reinterpret_cast<float4*>(bb) = *reinterpret_cast<const float4*>(&Ws[kk][tx * 4]);
            #pragma unroll
            for (int i = 0; i < 4; ++i)
                #pragma unroll
                for (int j = 0; j < 4; ++j)
                    c[i][j] = fmaf(a[i], bb[j], c[i][j]);
        }
    }

    #pragma unroll
    for (int i = 0; i < 4; ++i) {
        int mr = m0 + ty * 4 + i;
        if (mr < M) {
            #pragma unroll
            for (int j = 0; j < 4; ++j) {
                int nc = n0 + tx * 4 + j;
                if (nc < Ncols) Y[(size_t)mr * Ncols + nc] = c[i][j];
            }
        }
    }

    // fused column stats (OOB rows contribute zeros -> harmless)
    float cs[4], cq[4];
    #pragma unroll
    for (int j = 0; j < 4; ++j) {
        cs[j] = c[0][j] + c[1][j] + c[2][j] + c[3][j];
        cq[j] = fmaf(c[0][j], c[0][j], fmaf(c[1][j], c[1][j],
                 fmaf(c[2][j], c[2][j], c[3][j] * c[3][j])));
    }
    __syncthreads();
    #pragma unroll
    for (int j = 0; j < 4; ++j) { Xs[ty][tx * 4 + j] = cs[j]; Ws[ty][tx * 4 + j] = cq[j]; }
    __syncthreads();
    if (t < 64) {
        float a = 0.f, b2 = 0.f;
        #pragma unroll
        for (int r = 0; r < 16; ++r) { a += Xs[r][t]; b2 += Ws[r][t]; }
        atomicAdd(&sums[n0 + t], a);
        atomicAdd(&sums[Ncols + n0 + t], b2);
    }
}

// ---- normalize (finalize BN inline): out = Y*scale + shift, cols multiple of 64 ----
__global__ __launch_bounds__(256) void norm_apply(
    const float* __restrict__ Y, const float* __restrict__ sums,
    const float* __restrict__ g, const float* __restrict__ bb,
    float* __restrict__ out, int rows, int cols, float inv_rows, float post)
{
    __shared__ float sc_s[64], sh_s[64];
    const int t = threadIdx.x;
    const int c0 = blockIdx.x * 64;
    if (t < 64) {
        int c = c0 + t;
        float mu  = sums[c] * inv_rows;
        float var = fmaf(-mu, mu, sums[cols + c] * inv_rows);
        float s   = g[c] * rsqrtf(var + 1e-5f) * post;
        sc_s[t] = s;
        sh_s[t] = fmaf(-mu, s, bb[c] * post);
    }
    __syncthreads();
    const int c4 = (t & 15) * 4;
    float4 scv = *(const float4*)&sc_s[c4];
    float4 shv = *(const float4*)&sh_s[c4];
    for (int r = blockIdx.y * 16 + (t >> 4); r < rows; r += gridDim.y * 16) {
        size_t off = (size_t)r * cols + c0 + c4;
        float4 v = *(const float4*)(Y + off);
        v.x = fmaf(v.x, scv.x, shv.x);
        v.y = fmaf(v.y, scv.y, shv.y);
        v.z = fmaf(v.z, scv.z, shv.z);
        v.w = fmaf(v.w, scv.w, shv.w);
        *(float4*)(out + off) = v;
    }
}

// ---- bias remap: bt_r[h][dr*84+dc] = bf16(bias_table[h][rank]) ----
__global__ void bias_remap(const float* __restrict__ bias_table, const int* __restrict__ bias_idxs,
                           unsigned short* __restrict__ bt_r, int n_off)
{
    int i = blockIdx.x * 256 + threadIdx.x;
    if (i < 8 * N_K) {
        int h = i / N_K, j = i - h * N_K;
        bt_r[i] = f2bf(bias_table[h * n_off + bias_idxs[j]]);
    }
}

// ---- MFMA flash attention, 4-way key split ----
// grid (21 qtiles, 8 heads, 8 = b*4+ks). block 256 = 4 waves.
// Wave w owns q rows [q0+w*16, +16) and its complete online softmax (no cross-wave merge).
// Layouts (m89/m91/m74 verified): A: m=lane&15, k=(lane>>4)*8+j ; B: n=lane&15, same k ;
// C/D: col=lane&15, row=(lane>>4)*4+reg.
__global__ __launch_bounds__(256, 4) void attn_mfma(
    const float* __restrict__ kv_n, const float* __restrict__ q_n,
    const unsigned short* __restrict__ bt_r,
    float* __restrict__ pm, float* __restrict__ pl, float* __restrict__ pacc)
{
    const int qt = blockIdx.x, h = blockIdx.y;
    const int b = blockIdx.z >> 2, ks = blockIdx.z & 3;
    const int t = threadIdx.x;
    const int w = t >> 6, lane = t & 63;
    const int g = lane >> 4, ln = lane & 15;

    __shared__ unsigned short K_s[64][24];     // [key][d], pad 24: 16B-aligned b128 rows
    __shared__ unsigned short Vt_s[32][72];    // [v][key], pad 72
    __shared__ unsigned short P_s[4][16][72];  // per-wave P[q][key]
    __shared__ unsigned short bt_s[N_K];

    { // bias table (bf16) -> LDS
        const unsigned* src = (const unsigned*)(bt_r + h * N_K);
        unsigned* dst = (unsigned*)bt_s;
        for (int j = t; j < N_K / 2; j += 256) dst[j] = src[j];
    }

    const int q0 = qt * 64;

    // Q A-fragment (constant over key loop); k=d in [0,16) -> lane groups 2,3 are zero pad
    short8 qfrag = (short8)0;
    if (lane < 32) {
        const float* qp = q_n + ((size_t)(b * N_Q + q0 + w * 16 + ln) * NH_KD + h * 16 + g * 8);
        float4 a0 = *(const float4*)qp;
        float4 a1 = *(const float4*)(qp + 4);
        qfrag[0] = (short)f2bf(a0.x); qfrag[1] = (short)f2bf(a0.y);
        qfrag[2] = (short)f2bf(a0.z); qfrag[3] = (short)f2bf(a0.w);
        qfrag[4] = (short)f2bf(a1.x); qfrag[5] = (short)f2bf(a1.y);
        qfrag[6] = (short)f2bf(a1.z); qfrag[7] = (short)f2bf(a1.w);
    }

    // per-reg query geometry (rows of the C layout)
    int rq2[4], cq2[4];
    #pragma unroll
    for (int reg = 0; reg < 4; ++reg) {
        int qg = q0 + w * 16 + g * 4 + reg;
        rq2[reg] = (qg / 42) * 2;
        cq2[reg] = (qg % 42) * 2;
    }

    const int kstart = ks * 1344;
    const int kend = (kstart + 1344 < N_K) ? kstart + 1344 : N_K;

    // key geometry per 16-key subtile, column = ln; advanced incrementally
    int kr[4], kc[4];
    #pragma unroll
    for (int st = 0; st < 4; ++st) {
        int kg = kstart + st * 16 + ln;
        kr[st] = kg / 84;
        kc[st] = kg - kr[st] * 84;
    }

    float m[4], l[4];
    #pragma unroll
    for (int r = 0; r < 4; ++r) { m[r] = -1e30f; l[r] = 0.f; }
    f32x4 acc0 = {0.f, 0.f, 0.f, 0.f}, acc1 = {0.f, 0.f, 0.f, 0.f};
    const f32x4 zero4 = {0.f, 0.f, 0.f, 0.f};

    for (int k0 = kstart; k0 < kend; k0 += 64) {
        __syncthreads();   // prior tile's K/V fragment reads complete
        { // stage K tile: 64 keys x 16 d, fp32 -> bf16
            int kk = t >> 2, c4 = (t & 3) * 4;
            int kg = k0 + kk;
            float4 v = make_float4(0.f, 0.f, 0.f, 0.f);
            if (kg < N_K) v = *(const float4*)(kv_n + (size_t)(b * N_K + kg) * H_KV + h * 48 + c4);
            ushort4 u; u.x = f2bf(v.x); u.y = f2bf(v.y); u.z = f2bf(v.z); u.w = f2bf(v.w);
            *(ushort4*)&K_s[kk][c4] = u;
        }
        #pragma unroll
        for (int i = 0; i < 2; ++i) { // stage V transposed: Vt[v][key]
            int f = t + i * 256;
            int kk = f & 63, v4 = (f >> 6) * 4;
            int kg = k0 + kk;
            float4 v = make_float4(0.f, 0.f, 0.f, 0.f);
            if (kg < N_K) v = *(const float4*)(kv_n + (size_t)(b * N_K + kg) * H_KV + h * 48 + 16 + v4);
            Vt_s[v4 + 0][kk] = f2bf(v.x);
            Vt_s[v4 + 1][kk] = f2bf(v.y);
            Vt_s[v4 + 2][kk] = f2bf(v.z);
            Vt_s[v4 + 3][kk] = f2bf(v.w);
        }
        __syncthreads();

        // QK^T: four 16q x 16key tiles
        f32x4 sf[4];
        #pragma unroll
        for (int st = 0; st < 4; ++st) {
            short8 bf = (short8)0;
            if (lane < 32) bf = *(const short8*)&K_s[st * 16 + ln][g * 8];
            sf[st] = __builtin_amdgcn_mfma_f32_16x16x32_bf16(qfrag, bf, zero4, 0, 0, 0);
        }

        // bias + mask, row max
        float sc[4][4];
        float rmax[4] = {-1e30f, -1e30f, -1e30f, -1e30f};
        #pragma unroll
        for (int st = 0; st < 4; ++st) {
            bool valid = (k0 + st * 16 + ln) < N_K;
            #pragma unroll
            for (int reg = 0; reg < 4; ++reg) {
                int dr = rq2[reg] - kr[st]; dr = dr < 0 ? -dr : dr;
                int dc = cq2[reg] - kc[st]; dc = dc < 0 ? -dc : dc;
                float bias = __uint_as_float(((unsigned)bt_s[dr * 84 + dc]) << 16);
                float v = sf[st][reg] + bias;   // q pre-scaled by 0.25
                v = valid ? v : -1e30f;
                sc[st][reg] = v;
                rmax[reg] = fmaxf(rmax[reg], v);
            }
        }
        #pragma unroll
        for (int reg = 0; reg < 4; ++reg) {
            float r = rmax[reg];
            r = fmaxf(r, __shfl_xor(r, 1, 16));
            r = fmaxf(r, __shfl_xor(r, 2, 16));
            r = fmaxf(r, __shfl_xor(r, 4, 16));
            r = fmaxf(r, __shfl_xor(r, 8, 16));
            rmax[reg] = r;
        }

        // online update + P -> LDS (bf16)
        #pragma unroll
        for (int reg = 0; reg < 4; ++reg) {
            float mn = fmaxf(m[reg], rmax[reg]);
            float alpha = __expf(m[reg] - mn);
            m[reg] = mn;
            l[reg] *= alpha;
            acc0[reg] *= alpha;
            acc1[reg] *= alpha;
            #pragma unroll
            for (int st = 0; st < 4; ++st) {
                float p = __expf(sc[st][reg] - mn);
                l[reg] += p;
                P_s[w][g * 4 + reg][st * 16 + ln] = f2bf(p);
            }
        }

        // PV: acc[nt] += P(16q x 64k) * V(64k x 32v); per-wave P_s, waitcnt orders RAW
        #pragma unroll
        for (int kt = 0; kt < 2; ++kt) {
            short8 af = *(const short8*)&P_s[w][ln][g * 8 + kt * 32];
            short8 b0 = *(const short8*)&Vt_s[ln][g * 8 + kt * 32];
            short8 b1 = *(const short8*)&Vt_s[ln + 16][g * 8 + kt * 32];
            acc0 = __builtin_amdgcn_mfma_f32_16x16x32_bf16(af, b0, acc0, 0, 0, 0);
            acc1 = __builtin_amdgcn_mfma_f32_16x16x32_bf16(af, b1, acc1, 0, 0, 0);
        }

        // advance key geometry by 64
        #pragma unroll
        for (int st = 0; st < 4; ++st) {
            kc[st] += 64;
            if (kc[st] >= 84) { kc[st] -= 84; kr[st] += 1; }
        }
    }

    // row-sum of l partials
    #pragma unroll
    for (int reg = 0; reg < 4; ++reg) {
        float s = l[reg];
        s += __shfl_xor(s, 1, 16);
        s += __shfl_xor(s, 2, 16);
        s += __shfl_xor(s, 4, 16);
        s += __shfl_xor(s, 8, 16);
        l[reg] = s;
    }

    const int rbase = (b * 8 + h) * N_Q + q0 + w * 16;
    #pragma unroll
    for (int reg = 0; reg < 4; ++reg) {
        int prow = ks * NROWS + rbase + g * 4 + reg;
        pacc[(size_t)prow * 32 + ln]      = acc0[reg];
        pacc[(size_t)prow * 32 + 16 + ln] = acc1[reg];
        if (ln == 0) { pm[prow] = m[reg]; pl[prow] = l[reg]; }
    }
}

// ---- combine 4 key-split partials + hardswish ----
__global__ __launch_bounds__(256) void combine_kernel(const float* __restrict__ pm,
                                                      const float* __restrict__ pl,
                                                      const float* __restrict__ pacc,
                                                      float* __restrict__ attn_o)
{
    int i = blockIdx.x * 256 + threadIdx.x;
    int r = i >> 5, e = i & 31;
    float m0 = pm[r], m1 = pm[NROWS + r], m2 = pm[2 * NROWS + r], m3 = pm[3 * NROWS + r];
    float M = fmaxf(fmaxf(m0, m1), fmaxf(m2, m3));
    float w0 = __expf(m0 - M), w1 = __expf(m1 - M), w2 = __expf(m2 - M), w3 = __expf(m3 - M);
    float L = pl[r] * w0 + pl[NROWS + r] * w1 + pl[2 * NROWS + r] * w2 + pl[3 * NROWS + r] * w3;
    float v = pacc[(size_t)r * 32 + e] * w0 + pacc[(size_t)(NROWS + r) * 32 + e] * w1
            + pacc[(size_t)(2 * NROWS + r) * 32 + e] * w2 + pacc[(size_t)(3 * NROWS + r) * 32 + e] * w3;
    v /= L;
    float hs = v * fminf(fmaxf(v + 3.f, 0.f), 6.f) * (1.f / 6.f);
    int q = r % N_Q;
    int bh = r / N_Q;
    int hh = bh & 7, b = bh >> 3;
    attn_o[(size_t)(b * N_Q + q) * 256 + hh * 32 + e] = hs;
}

extern "C" void kernel_launch(void* const* d_in, const int* in_sizes, int n_in,
                              void* d_out, int out_size, void* d_ws, size_t ws_size,
                              hipStream_t stream) {
    (void)n_in; (void)out_size; (void)ws_size;
    const float* x      = (const float*)d_in[0];
    const float* kv_w   = (const float*)d_in[1];
    const float* kv_g   = (const float*)d_in[2];
    const float* kv_b   = (const float*)d_in[3];
    const float* q_w    = (const float*)d_in[4];
    const float* q_g    = (const float*)d_in[5];
    const float* q_b    = (const float*)d_in[6];
    const float* proj_w = (const float*)d_in[7];
    const float* proj_g = (const float*)d_in[8];
    const float* proj_b = (const float*)d_in[9];
    const float* bias_table = (const float*)d_in[10];
    const int*   bias_idxs  = (const int*)d_in[11];
    const int    n_off = in_sizes[10] / 8;
    float* out = (float*)d_out;

    float* ws = (float*)d_ws;
    float* kv_y     = ws;                          // 10584*384
    float* q_y      = kv_y + 10584 * 384;          // 2688*128
    float* attn_o   = q_y + 2688 * 128;            // 2688*256
    float* pacc     = attn_o + 2688 * 256;         // 4*21504*32
    float* proj_y   = pacc;                        // overlays pacc (dead after combine)
    float* pm       = pacc + 4 * NROWS * 32;
    float* pl       = pm + 4 * NROWS;
    float* sums_kv  = pl + 4 * NROWS;              // 768
    float* sums_q   = sums_kv + 768;               // 256
    float* sums_p   = sums_q + 256;                // 1024
    unsigned short* bt_r = (unsigned short*)(sums_p + 1024);  // 8*5292 bf16

    zero_f<<<8, 256, 0, stream>>>(sums_kv, 2048);

    // kv = x @ kv_w^T (+stats), then BN in place
    gemm_nt<<<dim3(6, 166), 256, 0, stream>>>(x, kv_w, kv_y, sums_kv, 10584, 384, 0);
    // q = xs @ q_w^T (+stats), BN*0.25 in place (attention scale folded)
    gemm_nt<<<dim3(2, 42), 256, 0, stream>>>(x, q_w, q_y, sums_q, 2688, 128, 1);
    // per-head remapped bias (independent of GEMMs)
    bias_remap<<<166, 256, 0, stream>>>(bias_table, bias_idxs, bt_r, n_off);

    norm_apply<<<dim3(6, 84), 256, 0, stream>>>(kv_y, sums_kv, kv_g, kv_b, kv_y,
                                                10584, 384, 1.f / 10584.f, 1.f);
    norm_apply<<<dim3(2, 84), 256, 0, stream>>>(q_y, sums_q, q_g, q_b, q_y,
                                                2688, 128, 1.f / 2688.f, 0.25f);

    // MFMA flash attention -> partials -> combine(+hardswish)
    attn_mfma<<<dim3(21, 8, 8), 256, 0, stream>>>(kv_y, q_y, bt_r, pm, pl, pacc);
    combine_kernel<<<2688, 256, 0, stream>>>(pm, pl, pacc, attn_o);

    // proj = hs @ proj_w^T (+stats), BN -> out
    gemm_nt<<<dim3(8, 42), 256, 0, stream>>>(attn_o, proj_w, proj_y, sums_p, 2688, 512, 0);
    norm_apply<<<dim3(8, 84), 256, 0, stream>>>(proj_y, sums_p, proj_g, proj_b, out,
                                                2688, 512, 1.f / 2688.f, 1.f);
}